// Round 1
// 428.203 us; speedup vs baseline: 1.0077x; 1.0077x over previous
//
#include <hip/hip_runtime.h>
#include <hip/hip_bf16.h>

#define N_NODES 50000
#define N_EDGES 800000
#define IN_C 512
#define HID_C 256
#define OUT_C 128
#define SCAN_BLOCKS 49  // ceil(50000 / 1024)

typedef short bf16x8 __attribute__((ext_vector_type(8)));
typedef float f32x4 __attribute__((ext_vector_type(4)));

__device__ __forceinline__ float bf2f(unsigned short u) {
    return __uint_as_float(((unsigned)u) << 16);
}
__device__ __forceinline__ unsigned short f2bf(float f) {
    __hip_bfloat16 h = __float2bfloat16(f);
    return *(unsigned short*)&h;
}

// ---------------------------------------------------------------- CSR build
__global__ void zero_counts_kernel(int* __restrict__ counts) {
    int i = blockIdx.x * blockDim.x + threadIdx.x;
    if (i < N_NODES) counts[i] = 0;
}

__global__ void count_kernel(const int* __restrict__ ei, int* __restrict__ counts) {
    int e = blockIdx.x * blockDim.x + threadIdx.x;
    if (e < N_EDGES) atomicAdd(&counts[ei[N_EDGES + e]], 1);
}

__global__ __launch_bounds__(256) void scan_part_kernel(const int* __restrict__ counts,
                                                        int* __restrict__ excl,
                                                        int* __restrict__ bsums) {
    __shared__ int tsum[256];
    const int t = threadIdx.x;
    const int base = blockIdx.x * 1024 + t * 4;
    int v[4];
    int s = 0;
#pragma unroll
    for (int j = 0; j < 4; j++) {
        int idx = base + j;
        v[j] = (idx < N_NODES) ? counts[idx] : 0;
        s += v[j];
    }
    tsum[t] = s;
    __syncthreads();
    for (int off = 1; off < 256; off <<= 1) {
        int add = (t >= off) ? tsum[t - off] : 0;
        __syncthreads();
        tsum[t] += add;
        __syncthreads();
    }
    int run = tsum[t] - s;
#pragma unroll
    for (int j = 0; j < 4; j++) {
        int idx = base + j;
        if (idx < N_NODES) excl[idx] = run;
        run += v[j];
    }
    if (t == 255) bsums[blockIdx.x] = tsum[255];
}

// wave-parallel exclusive scan of the 49 block sums
__global__ void scan_sums_kernel(int* __restrict__ bsums) {
    int ln = threadIdx.x;  // 64 threads = 1 wave
    int v = (ln < SCAN_BLOCKS) ? bsums[ln] : 0;
    for (int off = 1; off < 64; off <<= 1) {
        int u = __shfl_up(v, off, 64);
        if (ln >= off) v += u;
    }
    int excl = __shfl_up(v, 1, 64);
    if (ln == 0) excl = 0;
    if (ln < SCAN_BLOCKS) bsums[ln] = excl;
}

__global__ void add_dinv_kernel(int* __restrict__ offsets, const int* __restrict__ bsums,
                                int* __restrict__ woff, const int* __restrict__ counts,
                                float* __restrict__ dinv) {
    int i = blockIdx.x * blockDim.x + threadIdx.x;
    if (i < N_NODES) {
        int o = offsets[i] + bsums[i >> 10];
        offsets[i] = o;
        woff[i] = o;
        dinv[i] = rsqrtf(1.0f + (float)counts[i]);
    }
    if (i == 0) offsets[N_NODES] = N_EDGES;
}

// packed edge record: {src, bits(dinv[src])} -> one 8B dependent load per edge
// in the gather (was two 4B loads from two arrays), one 8B store here.
__global__ void fill_kernel(const int* __restrict__ ei, int* __restrict__ woff,
                            const float* __restrict__ dinv,
                            int2* __restrict__ sedge) {
    int e = blockIdx.x * blockDim.x + threadIdx.x;
    if (e < N_EDGES) {
        int s = ei[e];
        int d = ei[N_EDGES + e];
        int pos = atomicAdd(&woff[d], 1);
        sedge[pos] = make_int2(s, __float_as_int(dinv[s]));
    }
}

// ---------------------------------------------------------------- casts
__global__ __launch_bounds__(256) void cast_x_kernel(const float* __restrict__ x,
                                                     unsigned short* __restrict__ xb) {
    size_t i = ((size_t)blockIdx.x * 256 + threadIdx.x) * 4;  // grid sized exactly
    float4 v = *(const float4*)&x[i];
    ushort4 o;
    o.x = f2bf(v.x); o.y = f2bf(v.y); o.z = f2bf(v.z); o.w = f2bf(v.w);
    *(ushort4*)&xb[i] = o;
}

// WT[n][k] = bf16(W[k][n]); grid covers N*K exactly
__global__ __launch_bounds__(256) void tcast_kernel(const float* __restrict__ W,
                                                    unsigned short* __restrict__ WT,
                                                    int K, int N) {
    int idx = blockIdx.x * 256 + threadIdx.x;
    int n = idx / K, k = idx - n * K;
    WT[idx] = f2bf(W[(size_t)k * N + n]);
}

// ---------------------------------------------------------------- MFMA GEMM
// C[M,N](bf16) = A[M,K](bf16) @ BT[N,K](bf16)^T. 128x128 block tile, BK=32,
// 256 threads = 4 waves, each wave a 64x64 quadrant via 4x4 of 16x16x32 MFMA.
__global__ __launch_bounds__(256) void mfma_gemm_bt(const unsigned short* __restrict__ A,
                                                    const unsigned short* __restrict__ BT,
                                                    unsigned short* __restrict__ C,
                                                    int M, int N, int K) {
    __shared__ unsigned short As[128 * 32];  // [row][k] 64B rows
    __shared__ unsigned short Bs[128 * 32];

    const int tid = threadIdx.x;
    const int w = tid >> 6;
    const int ln = tid & 63;
    const int br = blockIdx.y * 128;
    const int bc = blockIdx.x * 128;

    const int quad = ln >> 4;
    const int l16 = ln & 15;
    const int wr = (w >> 1) * 64;
    const int wc = (w & 1) * 64;

    const int crow = ln >> 2;
    const int koff = (ln & 3) * 8;

    f32x4 acc[4][4];
#pragma unroll
    for (int mt = 0; mt < 4; mt++)
#pragma unroll
        for (int nt = 0; nt < 4; nt++) acc[mt][nt] = (f32x4){0.f, 0.f, 0.f, 0.f};

    for (int kk = 0; kk < K; kk += 32) {
#pragma unroll
        for (int t = 0; t < 2; t++) {
            int c = w + t * 4;
            int row = br + c * 16 + crow;
            row = row < M ? row : M - 1;  // clamp (dup read, stores guarded)
            const unsigned short* gp = A + (size_t)row * K + kk + koff;
            unsigned short* lp = As + c * 512 + ln * 8;
            __builtin_amdgcn_global_load_lds((const __attribute__((address_space(1))) void*)gp,
                                             (__attribute__((address_space(3))) void*)lp,
                                             16, 0, 0);
        }
#pragma unroll
        for (int t = 0; t < 2; t++) {
            int c = w + t * 4;
            int row = bc + c * 16 + crow;
            const unsigned short* gp = BT + (size_t)row * K + kk + koff;
            unsigned short* lp = Bs + c * 512 + ln * 8;
            __builtin_amdgcn_global_load_lds((const __attribute__((address_space(1))) void*)gp,
                                             (__attribute__((address_space(3))) void*)lp,
                                             16, 0, 0);
        }
        __syncthreads();

        bf16x8 af[4], bfr[4];
#pragma unroll
        for (int mt = 0; mt < 4; mt++)
            af[mt] = *(const bf16x8*)&As[(wr + mt * 16 + l16) * 32 + quad * 8];
#pragma unroll
        for (int nt = 0; nt < 4; nt++)
            bfr[nt] = *(const bf16x8*)&Bs[(wc + nt * 16 + l16) * 32 + quad * 8];
#pragma unroll
        for (int mt = 0; mt < 4; mt++)
#pragma unroll
            for (int nt = 0; nt < 4; nt++)
                acc[mt][nt] = __builtin_amdgcn_mfma_f32_16x16x32_bf16(af[mt], bfr[nt],
                                                                      acc[mt][nt], 0, 0, 0);
        __syncthreads();
    }

#pragma unroll
    for (int mt = 0; mt < 4; mt++) {
#pragma unroll
        for (int r = 0; r < 4; r++) {
            int gr = br + wr + mt * 16 + quad * 4 + r;
            if (gr < M) {
#pragma unroll
                for (int nt = 0; nt < 4; nt++) {
                    int gc = bc + wc + nt * 16 + l16;
                    C[(size_t)gr * N + gc] = f2bf(acc[mt][nt][r]);
                }
            }
        }
    }
}

// ------------------------------------------------------- gather aggregation
// One wave per node. Wave splits into NG = 64/(C/8) groups; each group owns
// an edge substream (stride NG) and loads full rows as 16B bf16x8 per lane.
// 4-deep edge unroll: 4 row-load instructions (4KB/wave) in flight, and the
// index->row dependent chain exposed once per 4*NG edges (was per 2*NG).
// Partial sums combined across groups with shfl_xor; group 0 writes.
// out[i,:] = relu?( dinv[i]^2*H[i,:] + b + sum_e dinv[i]*w_e*H[src,:] )
template <int C, bool RELU, bool BF16_OUT>
__global__ __launch_bounds__(256) void gather_agg_kernel(const int* __restrict__ offsets,
                                                         const int2* __restrict__ sedge,
                                                         const unsigned short* __restrict__ H,
                                                         const float* __restrict__ dinv,
                                                         const float* __restrict__ bias,
                                                         void* __restrict__ outv) {
    constexpr int G = C / 8;    // lanes per group: 32 (C=256), 16 (C=128)
    constexpr int NG = 64 / G;  // groups per wave: 2, 4
    const int node = blockIdx.x * 4 + (threadIdx.x >> 6);
    if (node >= N_NODES) return;
    const int ln = threadIdx.x & 63;
    const int g = ln / G;
    const int l = ln % G;
    const int c0 = l * 8;
    const float di = dinv[node];

    float acc[8] = {};
    if (g == 0) {  // self term + bias exactly once
        bf16x8 h = *(const bf16x8*)&H[(size_t)node * C + c0];
#pragma unroll
        for (int j = 0; j < 8; j++)
            acc[j] = di * di * bf2f((unsigned short)h[j]) + bias[c0 + j];
    }

    int k = offsets[node] + g;
    const int k1 = offsets[node + 1];
    // 4-edge unroll per group: up to 4*NG row loads in flight per wave
    for (; k + 3 * NG < k1; k += 4 * NG) {
        int2 e0 = sedge[k];
        int2 e1 = sedge[k + NG];
        int2 e2 = sedge[k + 2 * NG];
        int2 e3 = sedge[k + 3 * NG];
        bf16x8 h0 = *(const bf16x8*)&H[(size_t)e0.x * C + c0];
        bf16x8 h1 = *(const bf16x8*)&H[(size_t)e1.x * C + c0];
        bf16x8 h2 = *(const bf16x8*)&H[(size_t)e2.x * C + c0];
        bf16x8 h3 = *(const bf16x8*)&H[(size_t)e3.x * C + c0];
        float w0 = di * __int_as_float(e0.y);
        float w1 = di * __int_as_float(e1.y);
        float w2 = di * __int_as_float(e2.y);
        float w3 = di * __int_as_float(e3.y);
#pragma unroll
        for (int j = 0; j < 8; j++) {
            acc[j] += w0 * bf2f((unsigned short)h0[j]);
            acc[j] += w1 * bf2f((unsigned short)h1[j]);
            acc[j] += w2 * bf2f((unsigned short)h2[j]);
            acc[j] += w3 * bf2f((unsigned short)h3[j]);
        }
    }
    for (; k < k1; k += NG) {
        int2 e0 = sedge[k];
        float w0 = di * __int_as_float(e0.y);
        bf16x8 h0 = *(const bf16x8*)&H[(size_t)e0.x * C + c0];
#pragma unroll
        for (int j = 0; j < 8; j++) acc[j] += w0 * bf2f((unsigned short)h0[j]);
    }

    // combine group partials (every lane ends with the full sum)
#pragma unroll
    for (int m = G; m < 64; m <<= 1) {
#pragma unroll
        for (int j = 0; j < 8; j++) acc[j] += __shfl_xor(acc[j], m, 64);
    }

    if (g == 0) {
        if (RELU) {
#pragma unroll
            for (int j = 0; j < 8; j++) acc[j] = fmaxf(acc[j], 0.0f);
        }
        if (BF16_OUT) {
            bf16x8 o;
#pragma unroll
            for (int j = 0; j < 8; j++) o[j] = (short)f2bf(acc[j]);
            *(bf16x8*)&((unsigned short*)outv)[(size_t)node * C + c0] = o;
        } else {
            float* out = (float*)outv;
            *(float4*)&out[(size_t)node * C + c0] = make_float4(acc[0], acc[1], acc[2], acc[3]);
            *(float4*)&out[(size_t)node * C + c0 + 4] = make_float4(acc[4], acc[5], acc[6], acc[7]);
        }
    }
}

// ---------------------------------------------------------------- launcher
extern "C" void kernel_launch(void* const* d_in, const int* in_sizes, int n_in,
                              void* d_out, int out_size, void* d_ws, size_t ws_size,
                              hipStream_t stream) {
    const float* x  = (const float*)d_in[0];
    const int*   ei = (const int*)d_in[1];
    const float* W1 = (const float*)d_in[2];
    const float* b1 = (const float*)d_in[3];
    const float* W2 = (const float*)d_in[4];
    const float* b2 = (const float*)d_in[5];
    float* out = (float*)d_out;

    // workspace layout (4-byte words). Total 21,082,180 words = 84.3 MiB
    // (< known-good 98 MiB; earlier 101.5 MiB overflowed and corrupted inputs).
    int*   counts     = (int*)d_ws;                          // 50048
    int*   offsets    = counts + 50048;                      // 50052 (+sentinel)
    int*   woff       = offsets + 50052;                     // 50048
    int*   bsums      = woff + 50048;                        // 64
    float* dinv       = (float*)(bsums + 64);                // 50048
    int2*  sedge      = (int2*)(dinv + 50048);               // 800000 int2 = 1.6M words
    unsigned short* W1T = (unsigned short*)(sedge + 800000);          // 131072 sh
    unsigned short* W2T = W1T + 131072;                               // 32768 sh
    unsigned short* xb  = W2T + 32768;                                // 25.6M sh
    unsigned short* H1  = xb + (size_t)N_NODES * IN_C;                // 12.8M sh
    unsigned short* A1b = xb;                                         // overlay
    unsigned short* H2  = xb + (size_t)N_NODES * HID_C;               // overlay

    // CSR build + norm
    zero_counts_kernel<<<(N_NODES + 255) / 256, 256, 0, stream>>>(counts);
    count_kernel<<<(N_EDGES + 255) / 256, 256, 0, stream>>>(ei, counts);
    scan_part_kernel<<<SCAN_BLOCKS, 256, 0, stream>>>(counts, offsets, bsums);
    scan_sums_kernel<<<1, 64, 0, stream>>>(bsums);
    add_dinv_kernel<<<(N_NODES + 255) / 256, 256, 0, stream>>>(offsets, bsums, woff, counts, dinv);
    fill_kernel<<<(N_EDGES + 255) / 256, 256, 0, stream>>>(ei, woff, dinv, sedge);

    // bf16 casts
    cast_x_kernel<<<(N_NODES * IN_C) / 1024, 256, 0, stream>>>(x, xb);
    tcast_kernel<<<(IN_C * HID_C) / 256, 256, 0, stream>>>(W1, W1T, IN_C, HID_C);
    tcast_kernel<<<(HID_C * OUT_C) / 256, 256, 0, stream>>>(W2, W2T, HID_C, OUT_C);

    // layer 1: H1 = xb @ W1T^T  (bf16 MFMA)
    {
        dim3 grid(HID_C / 128, (N_NODES + 127) / 128);
        mfma_gemm_bt<<<grid, 256, 0, stream>>>(xb, W1T, H1, N_NODES, HID_C, IN_C);
    }
    gather_agg_kernel<HID_C, true, true><<<(N_NODES + 3) / 4, 256, 0, stream>>>(
        offsets, sedge, H1, dinv, b1, (void*)A1b);

    // layer 2: H2 = A1b @ W2T^T  (relu already applied in gather1 output)
    {
        dim3 grid(OUT_C / 128, (N_NODES + 127) / 128);
        mfma_gemm_bt<<<grid, 256, 0, stream>>>(A1b, W2T, H2, N_NODES, OUT_C, HID_C);
    }
    gather_agg_kernel<OUT_C, false, false><<<(N_NODES + 3) / 4, 256, 0, stream>>>(
        offsets, sedge, H2, dinv, b2, (void*)out);
}

// Round 2
// 403.340 us; speedup vs baseline: 1.0698x; 1.0616x over previous
//
#include <hip/hip_runtime.h>
#include <hip/hip_bf16.h>

#define N_NODES 50000
#define N_EDGES 800000
#define IN_C 512
#define HID_C 256
#define OUT_C 128
#define SCAN_BLOCKS 49  // ceil(50000 / 1024)

typedef short bf16x8 __attribute__((ext_vector_type(8)));
typedef float f32x4 __attribute__((ext_vector_type(4)));
typedef float f32x2 __attribute__((ext_vector_type(2)));

__device__ __forceinline__ float bf2f(unsigned short u) {
    return __uint_as_float(((unsigned)u) << 16);
}
__device__ __forceinline__ unsigned short f2bf(float f) {
    __hip_bfloat16 h = __float2bfloat16(f);
    return *(unsigned short*)&h;
}
// decode 4 fp8(e4m3) from one dword, accumulate (unweighted) into a[0..3]
__device__ __forceinline__ void acc_fp8x4(int dw, float* a) {
    f32x2 lo = __builtin_amdgcn_cvt_pk_f32_fp8(dw, false);
    f32x2 hi = __builtin_amdgcn_cvt_pk_f32_fp8(dw, true);
    a[0] += lo[0]; a[1] += lo[1]; a[2] += hi[0]; a[3] += hi[1];
}
__device__ __forceinline__ unsigned char f2fp8(float f) {
    return (unsigned char)(__builtin_amdgcn_cvt_pk_fp8_f32(f, 0.0f, 0, false) & 0xff);
}

// ---------------------------------------------------------------- CSR build
__global__ void zero_counts_kernel(int* __restrict__ counts) {
    int i = blockIdx.x * blockDim.x + threadIdx.x;
    if (i < N_NODES) counts[i] = 0;
}

__global__ void count_kernel(const int* __restrict__ ei, int* __restrict__ counts) {
    int e = blockIdx.x * blockDim.x + threadIdx.x;
    if (e < N_EDGES) atomicAdd(&counts[ei[N_EDGES + e]], 1);
}

__global__ __launch_bounds__(256) void scan_part_kernel(const int* __restrict__ counts,
                                                        int* __restrict__ excl,
                                                        int* __restrict__ bsums) {
    __shared__ int tsum[256];
    const int t = threadIdx.x;
    const int base = blockIdx.x * 1024 + t * 4;
    int v[4];
    int s = 0;
#pragma unroll
    for (int j = 0; j < 4; j++) {
        int idx = base + j;
        v[j] = (idx < N_NODES) ? counts[idx] : 0;
        s += v[j];
    }
    tsum[t] = s;
    __syncthreads();
    for (int off = 1; off < 256; off <<= 1) {
        int add = (t >= off) ? tsum[t - off] : 0;
        __syncthreads();
        tsum[t] += add;
        __syncthreads();
    }
    int run = tsum[t] - s;
#pragma unroll
    for (int j = 0; j < 4; j++) {
        int idx = base + j;
        if (idx < N_NODES) excl[idx] = run;
        run += v[j];
    }
    if (t == 255) bsums[blockIdx.x] = tsum[255];
}

// wave-parallel exclusive scan of the 49 block sums
__global__ void scan_sums_kernel(int* __restrict__ bsums) {
    int ln = threadIdx.x;  // 64 threads = 1 wave
    int v = (ln < SCAN_BLOCKS) ? bsums[ln] : 0;
    for (int off = 1; off < 64; off <<= 1) {
        int u = __shfl_up(v, off, 64);
        if (ln >= off) v += u;
    }
    int excl = __shfl_up(v, 1, 64);
    if (ln == 0) excl = 0;
    if (ln < SCAN_BLOCKS) bsums[ln] = excl;
}

__global__ void add_dinv_kernel(int* __restrict__ offsets, const int* __restrict__ bsums,
                                int* __restrict__ woff, const int* __restrict__ counts,
                                float* __restrict__ dinv) {
    int i = blockIdx.x * blockDim.x + threadIdx.x;
    if (i < N_NODES) {
        int o = offsets[i] + bsums[i >> 10];
        offsets[i] = o;
        woff[i] = o;
        dinv[i] = rsqrtf(1.0f + (float)counts[i]);
    }
    if (i == 0) offsets[N_NODES] = N_EDGES;
}

// edge record is just src (4B): norm is folded into prescaled rows (GEMM
// epilogues scale row r by dinv[r]) and the dst factor applied at gather end.
__global__ void fill_kernel(const int* __restrict__ ei, int* __restrict__ woff,
                            int* __restrict__ sedge) {
    int e = blockIdx.x * blockDim.x + threadIdx.x;
    if (e < N_EDGES) {
        int s = ei[e];
        int d = ei[N_EDGES + e];
        int pos = atomicAdd(&woff[d], 1);
        sedge[pos] = s;
    }
}

// ---------------------------------------------------------------- casts
__global__ __launch_bounds__(256) void cast_x_kernel(const float* __restrict__ x,
                                                     unsigned short* __restrict__ xb) {
    size_t i = ((size_t)blockIdx.x * 256 + threadIdx.x) * 4;  // grid sized exactly
    float4 v = *(const float4*)&x[i];
    ushort4 o;
    o.x = f2bf(v.x); o.y = f2bf(v.y); o.z = f2bf(v.z); o.w = f2bf(v.w);
    *(ushort4*)&xb[i] = o;
}

// WT[n][k] = bf16(W[k][n]); grid covers N*K exactly
__global__ __launch_bounds__(256) void tcast_kernel(const float* __restrict__ W,
                                                    unsigned short* __restrict__ WT,
                                                    int K, int N) {
    int idx = blockIdx.x * 256 + threadIdx.x;
    int n = idx / K, k = idx - n * K;
    WT[idx] = f2bf(W[(size_t)k * N + n]);
}

// ---------------------------------------------------------------- MFMA GEMM
// C[M,N] = dinv[row] * (A[M,K](bf16) @ BT[N,K](bf16)^T), stored fp8(e4m3) or
// bf16. 128x128 tile, BK=32, 4 waves, each wave 64x64 via 4x4 of 16x16x32.
template <bool FP8_OUT>
__global__ __launch_bounds__(256) void mfma_gemm_bt(const unsigned short* __restrict__ A,
                                                    const unsigned short* __restrict__ BT,
                                                    void* __restrict__ Cv,
                                                    const float* __restrict__ dinv,
                                                    int M, int N, int K) {
    __shared__ unsigned short As[128 * 32];  // [row][k] 64B rows
    __shared__ unsigned short Bs[128 * 32];

    const int tid = threadIdx.x;
    const int w = tid >> 6;
    const int ln = tid & 63;
    const int br = blockIdx.y * 128;
    const int bc = blockIdx.x * 128;

    const int quad = ln >> 4;
    const int l16 = ln & 15;
    const int wr = (w >> 1) * 64;
    const int wc = (w & 1) * 64;

    const int crow = ln >> 2;
    const int koff = (ln & 3) * 8;

    f32x4 acc[4][4];
#pragma unroll
    for (int mt = 0; mt < 4; mt++)
#pragma unroll
        for (int nt = 0; nt < 4; nt++) acc[mt][nt] = (f32x4){0.f, 0.f, 0.f, 0.f};

    for (int kk = 0; kk < K; kk += 32) {
#pragma unroll
        for (int t = 0; t < 2; t++) {
            int c = w + t * 4;
            int row = br + c * 16 + crow;
            row = row < M ? row : M - 1;  // clamp (dup read, stores guarded)
            const unsigned short* gp = A + (size_t)row * K + kk + koff;
            unsigned short* lp = As + c * 512 + ln * 8;
            __builtin_amdgcn_global_load_lds((const __attribute__((address_space(1))) void*)gp,
                                             (__attribute__((address_space(3))) void*)lp,
                                             16, 0, 0);
        }
#pragma unroll
        for (int t = 0; t < 2; t++) {
            int c = w + t * 4;
            int row = bc + c * 16 + crow;
            const unsigned short* gp = BT + (size_t)row * K + kk + koff;
            unsigned short* lp = Bs + c * 512 + ln * 8;
            __builtin_amdgcn_global_load_lds((const __attribute__((address_space(1))) void*)gp,
                                             (__attribute__((address_space(3))) void*)lp,
                                             16, 0, 0);
        }
        __syncthreads();

        bf16x8 af[4], bfr[4];
#pragma unroll
        for (int mt = 0; mt < 4; mt++)
            af[mt] = *(const bf16x8*)&As[(wr + mt * 16 + l16) * 32 + quad * 8];
#pragma unroll
        for (int nt = 0; nt < 4; nt++)
            bfr[nt] = *(const bf16x8*)&Bs[(wc + nt * 16 + l16) * 32 + quad * 8];
#pragma unroll
        for (int mt = 0; mt < 4; mt++)
#pragma unroll
            for (int nt = 0; nt < 4; nt++)
                acc[mt][nt] = __builtin_amdgcn_mfma_f32_16x16x32_bf16(af[mt], bfr[nt],
                                                                      acc[mt][nt], 0, 0, 0);
        __syncthreads();
    }

#pragma unroll
    for (int mt = 0; mt < 4; mt++) {
#pragma unroll
        for (int r = 0; r < 4; r++) {
            int gr = br + wr + mt * 16 + quad * 4 + r;
            if (gr < M) {
                float ds = dinv[gr];
#pragma unroll
                for (int nt = 0; nt < 4; nt++) {
                    int gc = bc + wc + nt * 16 + l16;
                    float v = ds * acc[mt][nt][r];
                    if (FP8_OUT)
                        ((unsigned char*)Cv)[(size_t)gr * N + gc] = f2fp8(v);
                    else
                        ((unsigned short*)Cv)[(size_t)gr * N + gc] = f2bf(v);
                }
            }
        }
    }
}

// ------------------------------------------------------- gather aggregation
// Layer-1 gather: H rows are fp8(e4m3), prescaled by dinv[src]. One wave per
// node, 2 groups of 32 lanes; lane covers 8 channels (8B fp8 load).
// out = bf16( relu( dinv[node] * (self' + sum_e row'[src]) + bias ) )
__global__ __launch_bounds__(256) void gather1_fp8(const int* __restrict__ offsets,
                                                   const int* __restrict__ sedge,
                                                   const unsigned char* __restrict__ H,
                                                   const float* __restrict__ dinv,
                                                   const float* __restrict__ bias,
                                                   unsigned short* __restrict__ out) {
    const int node = blockIdx.x * 4 + (threadIdx.x >> 6);
    if (node >= N_NODES) return;
    const int ln = threadIdx.x & 63;
    const int g = ln >> 5;   // 2 groups
    const int l = ln & 31;
    const int c0 = l * 8;

    float acc[8] = {};
    if (g == 0) {  // self term exactly once (row already has dinv[node] folded)
        uint2 d = *(const uint2*)&H[(size_t)node * HID_C + c0];
        acc_fp8x4((int)d.x, acc);
        acc_fp8x4((int)d.y, acc + 4);
    }

    int k = offsets[node] + g;
    const int k1 = offsets[node + 1];
    for (; k + 6 < k1; k += 8) {  // 4-deep unroll, group stride 2
        int s0 = sedge[k], s1 = sedge[k + 2], s2 = sedge[k + 4], s3 = sedge[k + 6];
        uint2 d0 = *(const uint2*)&H[(size_t)s0 * HID_C + c0];
        uint2 d1 = *(const uint2*)&H[(size_t)s1 * HID_C + c0];
        uint2 d2 = *(const uint2*)&H[(size_t)s2 * HID_C + c0];
        uint2 d3 = *(const uint2*)&H[(size_t)s3 * HID_C + c0];
        acc_fp8x4((int)d0.x, acc); acc_fp8x4((int)d0.y, acc + 4);
        acc_fp8x4((int)d1.x, acc); acc_fp8x4((int)d1.y, acc + 4);
        acc_fp8x4((int)d2.x, acc); acc_fp8x4((int)d2.y, acc + 4);
        acc_fp8x4((int)d3.x, acc); acc_fp8x4((int)d3.y, acc + 4);
    }
    for (; k < k1; k += 2) {
        int s0 = sedge[k];
        uint2 d0 = *(const uint2*)&H[(size_t)s0 * HID_C + c0];
        acc_fp8x4((int)d0.x, acc);
        acc_fp8x4((int)d0.y, acc + 4);
    }

    // combine the 2 group partials
#pragma unroll
    for (int j = 0; j < 8; j++) acc[j] += __shfl_xor(acc[j], 32, 64);

    if (g == 0) {
        const float di = dinv[node];
        bf16x8 o;
#pragma unroll
        for (int j = 0; j < 8; j++)
            o[j] = (short)f2bf(fmaxf(di * acc[j] + bias[c0 + j], 0.0f));
        *(bf16x8*)&out[(size_t)node * HID_C + c0] = o;
    }
}

// Layer-2 gather: H rows bf16, prescaled by dinv[src]. 4 groups of 16 lanes;
// lane covers 8 channels (16B bf16 load). fp32 output.
__global__ __launch_bounds__(256) void gather2_bf16(const int* __restrict__ offsets,
                                                    const int* __restrict__ sedge,
                                                    const unsigned short* __restrict__ H,
                                                    const float* __restrict__ dinv,
                                                    const float* __restrict__ bias,
                                                    float* __restrict__ out) {
    const int node = blockIdx.x * 4 + (threadIdx.x >> 6);
    if (node >= N_NODES) return;
    const int ln = threadIdx.x & 63;
    const int g = ln >> 4;   // 4 groups
    const int l = ln & 15;
    const int c0 = l * 8;

    float acc[8] = {};
    if (g == 0) {
        bf16x8 h = *(const bf16x8*)&H[(size_t)node * OUT_C + c0];
#pragma unroll
        for (int j = 0; j < 8; j++) acc[j] = bf2f((unsigned short)h[j]);
    }

    int k = offsets[node] + g;
    const int k1 = offsets[node + 1];
    for (; k + 12 < k1; k += 16) {  // 4-deep unroll, group stride 4
        int s0 = sedge[k], s1 = sedge[k + 4], s2 = sedge[k + 8], s3 = sedge[k + 12];
        bf16x8 h0 = *(const bf16x8*)&H[(size_t)s0 * OUT_C + c0];
        bf16x8 h1 = *(const bf16x8*)&H[(size_t)s1 * OUT_C + c0];
        bf16x8 h2 = *(const bf16x8*)&H[(size_t)s2 * OUT_C + c0];
        bf16x8 h3 = *(const bf16x8*)&H[(size_t)s3 * OUT_C + c0];
#pragma unroll
        for (int j = 0; j < 8; j++) {
            acc[j] += bf2f((unsigned short)h0[j]);
            acc[j] += bf2f((unsigned short)h1[j]);
            acc[j] += bf2f((unsigned short)h2[j]);
            acc[j] += bf2f((unsigned short)h3[j]);
        }
    }
    for (; k < k1; k += 4) {
        int s0 = sedge[k];
        bf16x8 h0 = *(const bf16x8*)&H[(size_t)s0 * OUT_C + c0];
#pragma unroll
        for (int j = 0; j < 8; j++) acc[j] += bf2f((unsigned short)h0[j]);
    }

#pragma unroll
    for (int m = 16; m < 64; m <<= 1) {
#pragma unroll
        for (int j = 0; j < 8; j++) acc[j] += __shfl_xor(acc[j], m, 64);
    }

    if (g == 0) {
        const float di = dinv[node];
        float o[8];
#pragma unroll
        for (int j = 0; j < 8; j++) o[j] = di * acc[j] + bias[c0 + j];
        *(float4*)&out[(size_t)node * OUT_C + c0] = make_float4(o[0], o[1], o[2], o[3]);
        *(float4*)&out[(size_t)node * OUT_C + c0 + 4] = make_float4(o[4], o[5], o[6], o[7]);
    }
}

// ---------------------------------------------------------------- launcher
extern "C" void kernel_launch(void* const* d_in, const int* in_sizes, int n_in,
                              void* d_out, int out_size, void* d_ws, size_t ws_size,
                              hipStream_t stream) {
    const float* x  = (const float*)d_in[0];
    const int*   ei = (const int*)d_in[1];
    const float* W1 = (const float*)d_in[2];
    const float* b1 = (const float*)d_in[3];
    const float* W2 = (const float*)d_in[4];
    const float* b2 = (const float*)d_in[5];
    float* out = (float*)d_out;

    // workspace layout (4-byte words). Total ~17.1M words = 68.3 MiB
    // (< known-good 84.3 MiB).
    int*   counts     = (int*)d_ws;                          // 50048
    int*   offsets    = counts + 50048;                      // 50052 (+sentinel)
    int*   woff       = offsets + 50052;                     // 50048
    int*   bsums      = woff + 50048;                        // 64
    float* dinv       = (float*)(bsums + 64);                // 50048
    int*   sedge      = (int*)(dinv + 50048);                // 800000 (src only)
    unsigned short* W1T = (unsigned short*)(sedge + 800000);          // 131072 sh
    unsigned short* W2T = W1T + 131072;                               // 32768 sh
    unsigned short* xb  = W2T + 32768;                                // 25.6M sh
    unsigned char*  H1  = (unsigned char*)(xb + (size_t)N_NODES * IN_C);  // 12.8MB fp8
    unsigned short* A1b = xb;                                         // overlay
    unsigned short* H2  = xb + (size_t)N_NODES * HID_C;               // overlay

    // CSR build + norm
    zero_counts_kernel<<<(N_NODES + 255) / 256, 256, 0, stream>>>(counts);
    count_kernel<<<(N_EDGES + 255) / 256, 256, 0, stream>>>(ei, counts);
    scan_part_kernel<<<SCAN_BLOCKS, 256, 0, stream>>>(counts, offsets, bsums);
    scan_sums_kernel<<<1, 64, 0, stream>>>(bsums);
    add_dinv_kernel<<<(N_NODES + 255) / 256, 256, 0, stream>>>(offsets, bsums, woff, counts, dinv);
    fill_kernel<<<(N_EDGES + 255) / 256, 256, 0, stream>>>(ei, woff, sedge);

    // bf16 casts
    cast_x_kernel<<<(N_NODES * IN_C) / 1024, 256, 0, stream>>>(x, xb);
    tcast_kernel<<<(IN_C * HID_C) / 256, 256, 0, stream>>>(W1, W1T, IN_C, HID_C);
    tcast_kernel<<<(HID_C * OUT_C) / 256, 256, 0, stream>>>(W2, W2T, HID_C, OUT_C);

    // layer 1: H1 = fp8( dinv[row] * (xb @ W1T^T) )
    {
        dim3 grid(HID_C / 128, (N_NODES + 127) / 128);
        mfma_gemm_bt<true><<<grid, 256, 0, stream>>>(xb, W1T, (void*)H1, dinv,
                                                     N_NODES, HID_C, IN_C);
    }
    gather1_fp8<<<(N_NODES + 3) / 4, 256, 0, stream>>>(offsets, sedge, H1, dinv, b1, A1b);

    // layer 2: H2 = bf16( dinv[row] * (A1b @ W2T^T) )
    {
        dim3 grid(OUT_C / 128, (N_NODES + 127) / 128);
        mfma_gemm_bt<false><<<grid, 256, 0, stream>>>(A1b, W2T, (void*)H2, dinv,
                                                      N_NODES, OUT_C, HID_C);
    }
    gather2_bf16<<<(N_NODES + 3) / 4, 256, 0, stream>>>(offsets, sedge, H2, dinv, b2, out);
}

// Round 3
// 386.152 us; speedup vs baseline: 1.1174x; 1.0445x over previous
//
#include <hip/hip_runtime.h>
#include <hip/hip_bf16.h>

#define N_NODES 50000
#define N_EDGES 800000
#define IN_C 512
#define HID_C 256
#define OUT_C 128
#define SCAN_BLOCKS 49  // ceil(50000 / 1024)

typedef short bf16x8 __attribute__((ext_vector_type(8)));
typedef float f32x4 __attribute__((ext_vector_type(4)));
typedef float f32x2 __attribute__((ext_vector_type(2)));

__device__ __forceinline__ float bf2f(unsigned short u) {
    return __uint_as_float(((unsigned)u) << 16);
}
__device__ __forceinline__ unsigned short f2bf(float f) {
    __hip_bfloat16 h = __float2bfloat16(f);
    return *(unsigned short*)&h;
}
// decode 4 fp8(e4m3) from one dword, accumulate (unweighted) into a[0..3]
__device__ __forceinline__ void acc_fp8x4(int dw, float* a) {
    f32x2 lo = __builtin_amdgcn_cvt_pk_f32_fp8(dw, false);
    f32x2 hi = __builtin_amdgcn_cvt_pk_f32_fp8(dw, true);
    a[0] += lo[0]; a[1] += lo[1]; a[2] += hi[0]; a[3] += hi[1];
}
__device__ __forceinline__ unsigned char f2fp8(float f) {
    return (unsigned char)(__builtin_amdgcn_cvt_pk_fp8_f32(f, 0.0f, 0, false) & 0xff);
}

// ---------------------------------------------------------------- CSR build
__global__ void zero_counts_kernel(int* __restrict__ counts) {
    int i = blockIdx.x * blockDim.x + threadIdx.x;
    if (i < N_NODES) counts[i] = 0;
}

__global__ void count_kernel(const int* __restrict__ ei, int* __restrict__ counts) {
    int e = blockIdx.x * blockDim.x + threadIdx.x;
    if (e < N_EDGES) atomicAdd(&counts[ei[N_EDGES + e]], 1);
}

__global__ __launch_bounds__(256) void scan_part_kernel(const int* __restrict__ counts,
                                                        int* __restrict__ excl,
                                                        int* __restrict__ bsums) {
    __shared__ int tsum[256];
    const int t = threadIdx.x;
    const int base = blockIdx.x * 1024 + t * 4;
    int v[4];
    int s = 0;
#pragma unroll
    for (int j = 0; j < 4; j++) {
        int idx = base + j;
        v[j] = (idx < N_NODES) ? counts[idx] : 0;
        s += v[j];
    }
    tsum[t] = s;
    __syncthreads();
    for (int off = 1; off < 256; off <<= 1) {
        int add = (t >= off) ? tsum[t - off] : 0;
        __syncthreads();
        tsum[t] += add;
        __syncthreads();
    }
    int run = tsum[t] - s;
#pragma unroll
    for (int j = 0; j < 4; j++) {
        int idx = base + j;
        if (idx < N_NODES) excl[idx] = run;
        run += v[j];
    }
    if (t == 255) bsums[blockIdx.x] = tsum[255];
}

// wave-parallel exclusive scan of the 49 block sums
__global__ void scan_sums_kernel(int* __restrict__ bsums) {
    int ln = threadIdx.x;  // 64 threads = 1 wave
    int v = (ln < SCAN_BLOCKS) ? bsums[ln] : 0;
    for (int off = 1; off < 64; off <<= 1) {
        int u = __shfl_up(v, off, 64);
        if (ln >= off) v += u;
    }
    int excl = __shfl_up(v, 1, 64);
    if (ln == 0) excl = 0;
    if (ln < SCAN_BLOCKS) bsums[ln] = excl;
}

__global__ void add_dinv_kernel(int* __restrict__ offsets, const int* __restrict__ bsums,
                                int* __restrict__ woff, const int* __restrict__ counts,
                                float* __restrict__ dinv) {
    int i = blockIdx.x * blockDim.x + threadIdx.x;
    if (i < N_NODES) {
        int o = offsets[i] + bsums[i >> 10];
        offsets[i] = o;
        woff[i] = o;
        dinv[i] = rsqrtf(1.0f + (float)counts[i]);
    }
    if (i == 0) offsets[N_NODES] = N_EDGES;
}

// edge record is just src (4B): norm is folded into prescaled rows (GEMM
// epilogues scale row r by dinv[r]) and the dst factor applied at gather end.
__global__ void fill_kernel(const int* __restrict__ ei, int* __restrict__ woff,
                            int* __restrict__ sedge) {
    int e = blockIdx.x * blockDim.x + threadIdx.x;
    if (e < N_EDGES) {
        int s = ei[e];
        int d = ei[N_EDGES + e];
        int pos = atomicAdd(&woff[d], 1);
        sedge[pos] = s;
    }
}

// ---------------------------------------------------------------- casts
// WT[n][k] = bf16(W[k][n]); grid covers N*K exactly
__global__ __launch_bounds__(256) void tcast_kernel(const float* __restrict__ W,
                                                    unsigned short* __restrict__ WT,
                                                    int K, int N) {
    int idx = blockIdx.x * 256 + threadIdx.x;
    int n = idx / K, k = idx - n * K;
    WT[idx] = f2bf(W[(size_t)k * N + n]);
}

// -------------------------------------------------- fused cast+GEMM layer 1
// H1[M,256](fp8) = fp8( dinv[row] * (bf16(x[M,512]) @ W1T[256,512]^T) )
// BM=64, BN=256(=full N -> x read exactly once), BK=32. 256 thr = 4 waves,
// wave w owns cols [64w,64w+64) via 4x4 of 16x16x32 MFMA. A is reg-staged
// from fp32 with in-register bf16 convert (fuses away the cast_x pass);
// B staged via global_load_lds (W1T is 256KB, L2-resident).
__global__ __launch_bounds__(256) void gemm1_fused(const float* __restrict__ x,
                                                   const unsigned short* __restrict__ BT,
                                                   unsigned char* __restrict__ C,
                                                   const float* __restrict__ dinv) {
    __shared__ unsigned short As[64 * 32];   // 4 KB  [row][k]
    __shared__ unsigned short Bs[256 * 32];  // 16 KB [n][k]

    const int tid = threadIdx.x;
    const int w = tid >> 6;
    const int ln = tid & 63;
    const int br = blockIdx.x * 64;

    const int quad = ln >> 4;
    const int l16 = ln & 15;
    const int wc = w * 64;

    const int ar = tid >> 2;        // 0..63 A-row within tile
    const int ak = (tid & 3) * 8;   // k-offset 0,8,16,24

    int arow = br + ar;
    arow = arow < N_NODES ? arow : N_NODES - 1;  // clamp (stores guarded)
    const float* xrow = x + (size_t)arow * IN_C + ak;

    f32x4 acc[4][4];
#pragma unroll
    for (int mt = 0; mt < 4; mt++)
#pragma unroll
        for (int nt = 0; nt < 4; nt++) acc[mt][nt] = (f32x4){0.f, 0.f, 0.f, 0.f};

    for (int kk = 0; kk < IN_C; kk += 32) {
        // A: 8 fp32 -> 8 bf16 -> one 16B ds_write per thread
        float4 v0 = *(const float4*)(xrow + kk);
        float4 v1 = *(const float4*)(xrow + kk + 4);
        bf16x8 a8;
        a8[0] = (short)f2bf(v0.x); a8[1] = (short)f2bf(v0.y);
        a8[2] = (short)f2bf(v0.z); a8[3] = (short)f2bf(v0.w);
        a8[4] = (short)f2bf(v1.x); a8[5] = (short)f2bf(v1.y);
        a8[6] = (short)f2bf(v1.z); a8[7] = (short)f2bf(v1.w);
        *(bf16x8*)&As[ar * 32 + ak] = a8;
        // B: 4 x 16B global_load_lds per thread (rows tid>>2 + 64t)
#pragma unroll
        for (int t = 0; t < 4; t++) {
            int n = (tid >> 2) + 64 * t;
            const unsigned short* gp = BT + (size_t)n * IN_C + kk + ak;
            unsigned short* lp = Bs + t * 2048 + tid * 8;
            __builtin_amdgcn_global_load_lds((const __attribute__((address_space(1))) void*)gp,
                                             (__attribute__((address_space(3))) void*)lp,
                                             16, 0, 0);
        }
        __syncthreads();

        bf16x8 af[4], bfr[4];
#pragma unroll
        for (int mt = 0; mt < 4; mt++)
            af[mt] = *(const bf16x8*)&As[(mt * 16 + l16) * 32 + quad * 8];
#pragma unroll
        for (int nt = 0; nt < 4; nt++)
            bfr[nt] = *(const bf16x8*)&Bs[(wc + nt * 16 + l16) * 32 + quad * 8];
#pragma unroll
        for (int mt = 0; mt < 4; mt++)
#pragma unroll
            for (int nt = 0; nt < 4; nt++)
                acc[mt][nt] = __builtin_amdgcn_mfma_f32_16x16x32_bf16(af[mt], bfr[nt],
                                                                      acc[mt][nt], 0, 0, 0);
        __syncthreads();
    }

#pragma unroll
    for (int mt = 0; mt < 4; mt++) {
#pragma unroll
        for (int r = 0; r < 4; r++) {
            int gr = br + mt * 16 + quad * 4 + r;
            if (gr < N_NODES) {
                float ds = dinv[gr];
#pragma unroll
                for (int nt = 0; nt < 4; nt++) {
                    int gc = wc + nt * 16 + l16;
                    C[(size_t)gr * HID_C + gc] = f2fp8(ds * acc[mt][nt][r]);
                }
            }
        }
    }
}

// ---------------------------------------------------------------- MFMA GEMM
// C[M,N](bf16) = dinv[row] * (A[M,K](bf16) @ BT[N,K](bf16)^T). 128x128 tile,
// BK=32, 4 waves, each wave 64x64 via 4x4 of 16x16x32. (layer 2 only)
__global__ __launch_bounds__(256) void mfma_gemm_bt(const unsigned short* __restrict__ A,
                                                    const unsigned short* __restrict__ BT,
                                                    unsigned short* __restrict__ C,
                                                    const float* __restrict__ dinv,
                                                    int M, int N, int K) {
    __shared__ unsigned short As[128 * 32];  // [row][k] 64B rows
    __shared__ unsigned short Bs[128 * 32];

    const int tid = threadIdx.x;
    const int w = tid >> 6;
    const int ln = tid & 63;
    const int br = blockIdx.y * 128;
    const int bc = blockIdx.x * 128;

    const int quad = ln >> 4;
    const int l16 = ln & 15;
    const int wr = (w >> 1) * 64;
    const int wc = (w & 1) * 64;

    const int crow = ln >> 2;
    const int koff = (ln & 3) * 8;

    f32x4 acc[4][4];
#pragma unroll
    for (int mt = 0; mt < 4; mt++)
#pragma unroll
        for (int nt = 0; nt < 4; nt++) acc[mt][nt] = (f32x4){0.f, 0.f, 0.f, 0.f};

    for (int kk = 0; kk < K; kk += 32) {
#pragma unroll
        for (int t = 0; t < 2; t++) {
            int c = w + t * 4;
            int row = br + c * 16 + crow;
            row = row < M ? row : M - 1;  // clamp (dup read, stores guarded)
            const unsigned short* gp = A + (size_t)row * K + kk + koff;
            unsigned short* lp = As + c * 512 + ln * 8;
            __builtin_amdgcn_global_load_lds((const __attribute__((address_space(1))) void*)gp,
                                             (__attribute__((address_space(3))) void*)lp,
                                             16, 0, 0);
        }
#pragma unroll
        for (int t = 0; t < 2; t++) {
            int c = w + t * 4;
            int row = bc + c * 16 + crow;
            const unsigned short* gp = BT + (size_t)row * K + kk + koff;
            unsigned short* lp = Bs + c * 512 + ln * 8;
            __builtin_amdgcn_global_load_lds((const __attribute__((address_space(1))) void*)gp,
                                             (__attribute__((address_space(3))) void*)lp,
                                             16, 0, 0);
        }
        __syncthreads();

        bf16x8 af[4], bfr[4];
#pragma unroll
        for (int mt = 0; mt < 4; mt++)
            af[mt] = *(const bf16x8*)&As[(wr + mt * 16 + l16) * 32 + quad * 8];
#pragma unroll
        for (int nt = 0; nt < 4; nt++)
            bfr[nt] = *(const bf16x8*)&Bs[(wc + nt * 16 + l16) * 32 + quad * 8];
#pragma unroll
        for (int mt = 0; mt < 4; mt++)
#pragma unroll
            for (int nt = 0; nt < 4; nt++)
                acc[mt][nt] = __builtin_amdgcn_mfma_f32_16x16x32_bf16(af[mt], bfr[nt],
                                                                      acc[mt][nt], 0, 0, 0);
        __syncthreads();
    }

#pragma unroll
    for (int mt = 0; mt < 4; mt++) {
#pragma unroll
        for (int r = 0; r < 4; r++) {
            int gr = br + wr + mt * 16 + quad * 4 + r;
            if (gr < M) {
                float ds = dinv[gr];
#pragma unroll
                for (int nt = 0; nt < 4; nt++) {
                    int gc = bc + wc + nt * 16 + l16;
                    C[(size_t)gr * N + gc] = f2bf(ds * acc[mt][nt][r]);
                }
            }
        }
    }
}

// ------------------------------------------------------- gather aggregation
// Layer-1 gather: H rows are fp8(e4m3), prescaled by dinv[src]. One wave per
// node, 2 groups of 32 lanes; lane covers 8 channels (8B fp8 load).
// out = bf16( relu( dinv[node] * (self' + sum_e row'[src]) + bias ) )
__global__ __launch_bounds__(256) void gather1_fp8(const int* __restrict__ offsets,
                                                   const int* __restrict__ sedge,
                                                   const unsigned char* __restrict__ H,
                                                   const float* __restrict__ dinv,
                                                   const float* __restrict__ bias,
                                                   unsigned short* __restrict__ out) {
    const int node = blockIdx.x * 4 + (threadIdx.x >> 6);
    if (node >= N_NODES) return;
    const int ln = threadIdx.x & 63;
    const int g = ln >> 5;   // 2 groups
    const int l = ln & 31;
    const int c0 = l * 8;

    float acc[8] = {};
    if (g == 0) {  // self term exactly once (row already has dinv[node] folded)
        uint2 d = *(const uint2*)&H[(size_t)node * HID_C + c0];
        acc_fp8x4((int)d.x, acc);
        acc_fp8x4((int)d.y, acc + 4);
    }

    int k = offsets[node] + g;
    const int k1 = offsets[node + 1];
    for (; k + 6 < k1; k += 8) {  // 4-deep unroll, group stride 2
        int s0 = sedge[k], s1 = sedge[k + 2], s2 = sedge[k + 4], s3 = sedge[k + 6];
        uint2 d0 = *(const uint2*)&H[(size_t)s0 * HID_C + c0];
        uint2 d1 = *(const uint2*)&H[(size_t)s1 * HID_C + c0];
        uint2 d2 = *(const uint2*)&H[(size_t)s2 * HID_C + c0];
        uint2 d3 = *(const uint2*)&H[(size_t)s3 * HID_C + c0];
        acc_fp8x4((int)d0.x, acc); acc_fp8x4((int)d0.y, acc + 4);
        acc_fp8x4((int)d1.x, acc); acc_fp8x4((int)d1.y, acc + 4);
        acc_fp8x4((int)d2.x, acc); acc_fp8x4((int)d2.y, acc + 4);
        acc_fp8x4((int)d3.x, acc); acc_fp8x4((int)d3.y, acc + 4);
    }
    for (; k < k1; k += 2) {
        int s0 = sedge[k];
        uint2 d0 = *(const uint2*)&H[(size_t)s0 * HID_C + c0];
        acc_fp8x4((int)d0.x, acc);
        acc_fp8x4((int)d0.y, acc + 4);
    }

    // combine the 2 group partials
#pragma unroll
    for (int j = 0; j < 8; j++) acc[j] += __shfl_xor(acc[j], 32, 64);

    if (g == 0) {
        const float di = dinv[node];
        bf16x8 o;
#pragma unroll
        for (int j = 0; j < 8; j++)
            o[j] = (short)f2bf(fmaxf(di * acc[j] + bias[c0 + j], 0.0f));
        *(bf16x8*)&out[(size_t)node * HID_C + c0] = o;
    }
}

// Layer-2 gather: H rows bf16, prescaled by dinv[src]. 4 groups of 16 lanes;
// lane covers 8 channels (16B bf16 load). fp32 output.
__global__ __launch_bounds__(256) void gather2_bf16(const int* __restrict__ offsets,
                                                    const int* __restrict__ sedge,
                                                    const unsigned short* __restrict__ H,
                                                    const float* __restrict__ dinv,
                                                    const float* __restrict__ bias,
                                                    float* __restrict__ out) {
    const int node = blockIdx.x * 4 + (threadIdx.x >> 6);
    if (node >= N_NODES) return;
    const int ln = threadIdx.x & 63;
    const int g = ln >> 4;   // 4 groups
    const int l = ln & 15;
    const int c0 = l * 8;

    float acc[8] = {};
    if (g == 0) {
        bf16x8 h = *(const bf16x8*)&H[(size_t)node * OUT_C + c0];
#pragma unroll
        for (int j = 0; j < 8; j++) acc[j] = bf2f((unsigned short)h[j]);
    }

    int k = offsets[node] + g;
    const int k1 = offsets[node + 1];
    for (; k + 12 < k1; k += 16) {  // 4-deep unroll, group stride 4
        int s0 = sedge[k], s1 = sedge[k + 4], s2 = sedge[k + 8], s3 = sedge[k + 12];
        bf16x8 h0 = *(const bf16x8*)&H[(size_t)s0 * OUT_C + c0];
        bf16x8 h1 = *(const bf16x8*)&H[(size_t)s1 * OUT_C + c0];
        bf16x8 h2 = *(const bf16x8*)&H[(size_t)s2 * OUT_C + c0];
        bf16x8 h3 = *(const bf16x8*)&H[(size_t)s3 * OUT_C + c0];
#pragma unroll
        for (int j = 0; j < 8; j++) {
            acc[j] += bf2f((unsigned short)h0[j]);
            acc[j] += bf2f((unsigned short)h1[j]);
            acc[j] += bf2f((unsigned short)h2[j]);
            acc[j] += bf2f((unsigned short)h3[j]);
        }
    }
    for (; k < k1; k += 4) {
        int s0 = sedge[k];
        bf16x8 h0 = *(const bf16x8*)&H[(size_t)s0 * OUT_C + c0];
#pragma unroll
        for (int j = 0; j < 8; j++) acc[j] += bf2f((unsigned short)h0[j]);
    }

#pragma unroll
    for (int m = 16; m < 64; m <<= 1) {
#pragma unroll
        for (int j = 0; j < 8; j++) acc[j] += __shfl_xor(acc[j], m, 64);
    }

    if (g == 0) {
        const float di = dinv[node];
        float o[8];
#pragma unroll
        for (int j = 0; j < 8; j++) o[j] = di * acc[j] + bias[c0 + j];
        *(float4*)&out[(size_t)node * OUT_C + c0] = make_float4(o[0], o[1], o[2], o[3]);
        *(float4*)&out[(size_t)node * OUT_C + c0 + 4] = make_float4(o[4], o[5], o[6], o[7]);
    }
}

// ---------------------------------------------------------------- launcher
extern "C" void kernel_launch(void* const* d_in, const int* in_sizes, int n_in,
                              void* d_out, int out_size, void* d_ws, size_t ws_size,
                              hipStream_t stream) {
    const float* x  = (const float*)d_in[0];
    const int*   ei = (const int*)d_in[1];
    const float* W1 = (const float*)d_in[2];
    const float* b1 = (const float*)d_in[3];
    const float* W2 = (const float*)d_in[4];
    const float* b2 = (const float*)d_in[5];
    float* out = (float*)d_out;

    // workspace layout (4-byte words), same as known-good R2 (68.3 MiB).
    int*   counts     = (int*)d_ws;                          // 50048
    int*   offsets    = counts + 50048;                      // 50052 (+sentinel)
    int*   woff       = offsets + 50052;                     // 50048
    int*   bsums      = woff + 50048;                        // 64
    float* dinv       = (float*)(bsums + 64);                // 50048
    int*   sedge      = (int*)(dinv + 50048);                // 800000 (src only)
    unsigned short* W1T = (unsigned short*)(sedge + 800000);          // 131072 sh
    unsigned short* W2T = W1T + 131072;                               // 32768 sh
    unsigned short* xb  = W2T + 32768;                                // 25.6M sh region
    unsigned char*  H1  = (unsigned char*)(xb + (size_t)N_NODES * IN_C);  // 12.8MB fp8
    unsigned short* A1b = xb;                                         // overlay
    unsigned short* H2  = xb + (size_t)N_NODES * HID_C;               // overlay

    // CSR build + norm
    zero_counts_kernel<<<(N_NODES + 255) / 256, 256, 0, stream>>>(counts);
    count_kernel<<<(N_EDGES + 255) / 256, 256, 0, stream>>>(ei, counts);
    scan_part_kernel<<<SCAN_BLOCKS, 256, 0, stream>>>(counts, offsets, bsums);
    scan_sums_kernel<<<1, 64, 0, stream>>>(bsums);
    add_dinv_kernel<<<(N_NODES + 255) / 256, 256, 0, stream>>>(offsets, bsums, woff, counts, dinv);
    fill_kernel<<<(N_EDGES + 255) / 256, 256, 0, stream>>>(ei, woff, sedge);

    // weight casts (tiny)
    tcast_kernel<<<(IN_C * HID_C) / 256, 256, 0, stream>>>(W1, W1T, IN_C, HID_C);
    tcast_kernel<<<(HID_C * OUT_C) / 256, 256, 0, stream>>>(W2, W2T, HID_C, OUT_C);

    // layer 1: H1 = fp8( dinv[row] * (bf16(x) @ W1T^T) )  (cast fused, x read once)
    gemm1_fused<<<(N_NODES + 63) / 64, 256, 0, stream>>>(x, W1T, H1, dinv);
    gather1_fp8<<<(N_NODES + 3) / 4, 256, 0, stream>>>(offsets, sedge, H1, dinv, b1, A1b);

    // layer 2: H2 = bf16( dinv[row] * (A1b @ W2T^T) )
    {
        dim3 grid(OUT_C / 128, (N_NODES + 127) / 128);
        mfma_gemm_bt<<<grid, 256, 0, stream>>>(A1b, W2T, H2, dinv, N_NODES, OUT_C, HID_C);
    }
    gather2_bf16<<<(N_NODES + 3) / 4, 256, 0, stream>>>(offsets, sedge, H2, dinv, b2, out);
}

// Round 4
// 383.278 us; speedup vs baseline: 1.1258x; 1.0075x over previous
//
#include <hip/hip_runtime.h>
#include <hip/hip_bf16.h>

#define N_NODES 50000
#define N_EDGES 800000
#define IN_C 512
#define HID_C 256
#define OUT_C 128
#define SCAN_BLOCKS 49  // ceil(50000 / 1024)

typedef short bf16x8 __attribute__((ext_vector_type(8)));
typedef float f32x4 __attribute__((ext_vector_type(4)));
typedef float f32x2 __attribute__((ext_vector_type(2)));

__device__ __forceinline__ float bf2f(unsigned short u) {
    return __uint_as_float(((unsigned)u) << 16);
}
__device__ __forceinline__ unsigned short f2bf(float f) {
    __hip_bfloat16 h = __float2bfloat16(f);
    return *(unsigned short*)&h;
}
// decode 4 fp8(e4m3) from one dword, accumulate (unweighted) into a[0..3]
__device__ __forceinline__ void acc_fp8x4(int dw, float* a) {
    f32x2 lo = __builtin_amdgcn_cvt_pk_f32_fp8(dw, false);
    f32x2 hi = __builtin_amdgcn_cvt_pk_f32_fp8(dw, true);
    a[0] += lo[0]; a[1] += lo[1]; a[2] += hi[0]; a[3] += hi[1];
}
__device__ __forceinline__ unsigned char f2fp8(float f) {
    return (unsigned char)(__builtin_amdgcn_cvt_pk_fp8_f32(f, 0.0f, 0, false) & 0xff);
}
__device__ __forceinline__ void glds16(const void* gp, void* lp) {
    __builtin_amdgcn_global_load_lds((const __attribute__((address_space(1))) void*)gp,
                                     (__attribute__((address_space(3))) void*)lp, 16, 0, 0);
}

// ---------------------------------------------------------------- CSR build
__global__ void zero_counts_kernel(int* __restrict__ counts) {
    int i = blockIdx.x * blockDim.x + threadIdx.x;
    if (i < N_NODES) counts[i] = 0;
}

__global__ void count_kernel(const int* __restrict__ ei, int* __restrict__ counts) {
    int e = blockIdx.x * blockDim.x + threadIdx.x;
    if (e < N_EDGES) atomicAdd(&counts[ei[N_EDGES + e]], 1);
}

__global__ __launch_bounds__(256) void scan_part_kernel(const int* __restrict__ counts,
                                                        int* __restrict__ excl,
                                                        int* __restrict__ bsums) {
    __shared__ int tsum[256];
    const int t = threadIdx.x;
    const int base = blockIdx.x * 1024 + t * 4;
    int v[4];
    int s = 0;
#pragma unroll
    for (int j = 0; j < 4; j++) {
        int idx = base + j;
        v[j] = (idx < N_NODES) ? counts[idx] : 0;
        s += v[j];
    }
    tsum[t] = s;
    __syncthreads();
    for (int off = 1; off < 256; off <<= 1) {
        int add = (t >= off) ? tsum[t - off] : 0;
        __syncthreads();
        tsum[t] += add;
        __syncthreads();
    }
    int run = tsum[t] - s;
#pragma unroll
    for (int j = 0; j < 4; j++) {
        int idx = base + j;
        if (idx < N_NODES) excl[idx] = run;
        run += v[j];
    }
    if (t == 255) bsums[blockIdx.x] = tsum[255];
}

// wave-parallel exclusive scan of the 49 block sums
__global__ void scan_sums_kernel(int* __restrict__ bsums) {
    int ln = threadIdx.x;  // 64 threads = 1 wave
    int v = (ln < SCAN_BLOCKS) ? bsums[ln] : 0;
    for (int off = 1; off < 64; off <<= 1) {
        int u = __shfl_up(v, off, 64);
        if (ln >= off) v += u;
    }
    int excl = __shfl_up(v, 1, 64);
    if (ln == 0) excl = 0;
    if (ln < SCAN_BLOCKS) bsums[ln] = excl;
}

__global__ void add_dinv_kernel(int* __restrict__ offsets, const int* __restrict__ bsums,
                                int* __restrict__ woff, const int* __restrict__ counts,
                                float* __restrict__ dinv) {
    int i = blockIdx.x * blockDim.x + threadIdx.x;
    if (i < N_NODES) {
        int o = offsets[i] + bsums[i >> 10];
        offsets[i] = o;
        woff[i] = o;
        dinv[i] = rsqrtf(1.0f + (float)counts[i]);
    }
    if (i == 0) offsets[N_NODES] = N_EDGES;
}

// edge record is just src (4B): norm is folded into prescaled rows (GEMM
// epilogues scale row r by dinv[r]) and the dst factor applied at gather end.
__global__ void fill_kernel(const int* __restrict__ ei, int* __restrict__ woff,
                            int* __restrict__ sedge) {
    int e = blockIdx.x * blockDim.x + threadIdx.x;
    if (e < N_EDGES) {
        int s = ei[e];
        int d = ei[N_EDGES + e];
        int pos = atomicAdd(&woff[d], 1);
        sedge[pos] = s;
    }
}

// ---------------------------------------------------------------- casts
// WT[n][k] = bf16(W[k][n]); grid covers N*K exactly
__global__ __launch_bounds__(256) void tcast_kernel(const float* __restrict__ W,
                                                    unsigned short* __restrict__ WT,
                                                    int K, int N) {
    int idx = blockIdx.x * 256 + threadIdx.x;
    int n = idx / K, k = idx - n * K;
    WT[idx] = f2bf(W[(size_t)k * N + n]);
}

// -------------------------------------------------- fused cast+GEMM layer 1
// H1[M,256](fp8) = fp8( dinv[row] * (bf16(x[M,512]) @ W1T[256,512]^T) )
// BM=64, BN=256 (full N -> x read once), BK=32, double-buffered 2-phase:
// at step t, issue x(t+1) reg-loads + B(t+1) global_load_lds BEFORE the
// MFMAs of step t; cvt+ds_write A(t+1) after them; one barrier per step.
// Global latency hides under compute instead of being drained before it.
__global__ __launch_bounds__(256) void gemm1_fused(const float* __restrict__ x,
                                                   const unsigned short* __restrict__ BT,
                                                   unsigned char* __restrict__ C,
                                                   const float* __restrict__ dinv) {
    __shared__ unsigned short As[2][64 * 32];   // 2 x 4 KB  [row][k]
    __shared__ unsigned short Bs[2][256 * 32];  // 2 x 16 KB [n][k]

    const int tid = threadIdx.x;
    const int w = tid >> 6;
    const int ln = tid & 63;
    const int br = blockIdx.x * 64;

    const int quad = ln >> 4;
    const int l16 = ln & 15;
    const int wc = w * 64;

    const int ar = tid >> 2;        // 0..63 A-row within tile
    const int ak = (tid & 3) * 8;   // k-offset 0,8,16,24

    int arow = br + ar;
    arow = arow < N_NODES ? arow : N_NODES - 1;  // clamp (stores guarded)
    const float* xrow = x + (size_t)arow * IN_C + ak;
    const int brow = (tid >> 2);    // B row base per thread

    f32x4 acc[4][4];
#pragma unroll
    for (int mt = 0; mt < 4; mt++)
#pragma unroll
        for (int nt = 0; nt < 4; nt++) acc[mt][nt] = (f32x4){0.f, 0.f, 0.f, 0.f};

    // ---- prologue: stage k-step 0 into buffer 0
    {
        float4 v0 = *(const float4*)(xrow);
        float4 v1 = *(const float4*)(xrow + 4);
#pragma unroll
        for (int tt = 0; tt < 4; tt++) {
            const unsigned short* gp = BT + (size_t)(brow + 64 * tt) * IN_C + ak;
            glds16(gp, &Bs[0][tt * 2048 + tid * 8]);
        }
        bf16x8 a8;
        a8[0] = (short)f2bf(v0.x); a8[1] = (short)f2bf(v0.y);
        a8[2] = (short)f2bf(v0.z); a8[3] = (short)f2bf(v0.w);
        a8[4] = (short)f2bf(v1.x); a8[5] = (short)f2bf(v1.y);
        a8[6] = (short)f2bf(v1.z); a8[7] = (short)f2bf(v1.w);
        *(bf16x8*)&As[0][ar * 32 + ak] = a8;
    }
    __syncthreads();

    for (int t = 0; t < 16; t++) {
        const int buf = t & 1;
        const int nxt = buf ^ 1;
        const bool more = t < 15;
        float4 v0, v1;
        if (more) {  // issue next-step loads first (latency hides under MFMA)
            const int kk = (t + 1) * 32;
            v0 = *(const float4*)(xrow + kk);
            v1 = *(const float4*)(xrow + kk + 4);
#pragma unroll
            for (int tt = 0; tt < 4; tt++) {
                const unsigned short* gp = BT + (size_t)(brow + 64 * tt) * IN_C + kk + ak;
                glds16(gp, &Bs[nxt][tt * 2048 + tid * 8]);
            }
        }

        bf16x8 af[4], bfr[4];
#pragma unroll
        for (int mt = 0; mt < 4; mt++)
            af[mt] = *(const bf16x8*)&As[buf][(mt * 16 + l16) * 32 + quad * 8];
#pragma unroll
        for (int nt = 0; nt < 4; nt++)
            bfr[nt] = *(const bf16x8*)&Bs[buf][(wc + nt * 16 + l16) * 32 + quad * 8];
#pragma unroll
        for (int mt = 0; mt < 4; mt++)
#pragma unroll
            for (int nt = 0; nt < 4; nt++)
                acc[mt][nt] = __builtin_amdgcn_mfma_f32_16x16x32_bf16(af[mt], bfr[nt],
                                                                      acc[mt][nt], 0, 0, 0);
        if (more) {  // convert + stage next A (waits only on the x reg-loads)
            bf16x8 a8;
            a8[0] = (short)f2bf(v0.x); a8[1] = (short)f2bf(v0.y);
            a8[2] = (short)f2bf(v0.z); a8[3] = (short)f2bf(v0.w);
            a8[4] = (short)f2bf(v1.x); a8[5] = (short)f2bf(v1.y);
            a8[6] = (short)f2bf(v1.z); a8[7] = (short)f2bf(v1.w);
            *(bf16x8*)&As[nxt][ar * 32 + ak] = a8;
        }
        __syncthreads();
    }

#pragma unroll
    for (int mt = 0; mt < 4; mt++) {
#pragma unroll
        for (int r = 0; r < 4; r++) {
            int gr = br + mt * 16 + quad * 4 + r;
            if (gr < N_NODES) {
                float ds = dinv[gr];
#pragma unroll
                for (int nt = 0; nt < 4; nt++) {
                    int gc = wc + nt * 16 + l16;
                    C[(size_t)gr * HID_C + gc] = f2fp8(ds * acc[mt][nt][r]);
                }
            }
        }
    }
}

// ------------------------------------------------------ GEMM layer 2 (2-ph)
// H2[M,128](bf16) = bf16( dinv[row] * (A1b[M,256](bf16) @ W2T[128,256]^T) )
// BM=64, BN=128 (full N -> A read once), BK=32, double-buffered, both
// operands via global_load_lds. Wave w: rows (w>>1)*32, cols (w&1)*64.
__global__ __launch_bounds__(256) void gemm2_db(const unsigned short* __restrict__ A,
                                                const unsigned short* __restrict__ BT,
                                                unsigned short* __restrict__ C,
                                                const float* __restrict__ dinv) {
    __shared__ unsigned short As[2][64 * 32];   // 2 x 4 KB
    __shared__ unsigned short Bs[2][128 * 32];  // 2 x 8 KB

    const int tid = threadIdx.x;
    const int w = tid >> 6;
    const int ln = tid & 63;
    const int br = blockIdx.x * 64;

    const int quad = ln >> 4;
    const int l16 = ln & 15;
    const int wr = (w >> 1) * 32;
    const int wc = (w & 1) * 64;

    const int ak = (tid & 3) * 8;
    const int trow = tid >> 2;  // 0..63

    int arow = br + trow;
    arow = arow < N_NODES ? arow : N_NODES - 1;  // clamp (stores guarded)
    const unsigned short* agp0 = A + (size_t)arow * HID_C + ak;

    f32x4 acc[2][4];
#pragma unroll
    for (int mt = 0; mt < 2; mt++)
#pragma unroll
        for (int nt = 0; nt < 4; nt++) acc[mt][nt] = (f32x4){0.f, 0.f, 0.f, 0.f};

    // prologue: stage k-step 0
    glds16(agp0, &As[0][tid * 8]);
#pragma unroll
    for (int tt = 0; tt < 2; tt++) {
        const unsigned short* gp = BT + (size_t)(trow + 64 * tt) * HID_C + ak;
        glds16(gp, &Bs[0][tt * 2048 + tid * 8]);
    }
    __syncthreads();

    for (int t = 0; t < 8; t++) {
        const int buf = t & 1;
        const int nxt = buf ^ 1;
        if (t < 7) {
            const int kk = (t + 1) * 32;
            glds16(agp0 + kk, &As[nxt][tid * 8]);
#pragma unroll
            for (int tt = 0; tt < 2; tt++) {
                const unsigned short* gp = BT + (size_t)(trow + 64 * tt) * HID_C + kk + ak;
                glds16(gp, &Bs[nxt][tt * 2048 + tid * 8]);
            }
        }

        bf16x8 af[2], bfr[4];
#pragma unroll
        for (int mt = 0; mt < 2; mt++)
            af[mt] = *(const bf16x8*)&As[buf][(wr + mt * 16 + l16) * 32 + quad * 8];
#pragma unroll
        for (int nt = 0; nt < 4; nt++)
            bfr[nt] = *(const bf16x8*)&Bs[buf][(wc + nt * 16 + l16) * 32 + quad * 8];
#pragma unroll
        for (int mt = 0; mt < 2; mt++)
#pragma unroll
            for (int nt = 0; nt < 4; nt++)
                acc[mt][nt] = __builtin_amdgcn_mfma_f32_16x16x32_bf16(af[mt], bfr[nt],
                                                                      acc[mt][nt], 0, 0, 0);
        __syncthreads();
    }

#pragma unroll
    for (int mt = 0; mt < 2; mt++) {
#pragma unroll
        for (int r = 0; r < 4; r++) {
            int gr = br + wr + mt * 16 + quad * 4 + r;
            if (gr < N_NODES) {
                float ds = dinv[gr];
#pragma unroll
                for (int nt = 0; nt < 4; nt++) {
                    int gc = wc + nt * 16 + l16;
                    C[(size_t)gr * OUT_C + gc] = f2bf(ds * acc[mt][nt][r]);
                }
            }
        }
    }
}

// ------------------------------------------------------- gather aggregation
// Layer-1 gather: H rows are fp8(e4m3), prescaled by dinv[src]. One wave per
// node, 2 groups of 32 lanes; lane covers 8 channels (8B fp8 load).
// out = bf16( relu( dinv[node] * (self' + sum_e row'[src]) + bias ) )
__global__ __launch_bounds__(256) void gather1_fp8(const int* __restrict__ offsets,
                                                   const int* __restrict__ sedge,
                                                   const unsigned char* __restrict__ H,
                                                   const float* __restrict__ dinv,
                                                   const float* __restrict__ bias,
                                                   unsigned short* __restrict__ out) {
    const int node = blockIdx.x * 4 + (threadIdx.x >> 6);
    if (node >= N_NODES) return;
    const int ln = threadIdx.x & 63;
    const int g = ln >> 5;   // 2 groups
    const int l = ln & 31;
    const int c0 = l * 8;

    float acc[8] = {};
    if (g == 0) {  // self term exactly once (row already has dinv[node] folded)
        uint2 d = *(const uint2*)&H[(size_t)node * HID_C + c0];
        acc_fp8x4((int)d.x, acc);
        acc_fp8x4((int)d.y, acc + 4);
    }

    int k = offsets[node] + g;
    const int k1 = offsets[node + 1];
    for (; k + 6 < k1; k += 8) {  // 4-deep unroll, group stride 2
        int s0 = sedge[k], s1 = sedge[k + 2], s2 = sedge[k + 4], s3 = sedge[k + 6];
        uint2 d0 = *(const uint2*)&H[(size_t)s0 * HID_C + c0];
        uint2 d1 = *(const uint2*)&H[(size_t)s1 * HID_C + c0];
        uint2 d2 = *(const uint2*)&H[(size_t)s2 * HID_C + c0];
        uint2 d3 = *(const uint2*)&H[(size_t)s3 * HID_C + c0];
        acc_fp8x4((int)d0.x, acc); acc_fp8x4((int)d0.y, acc + 4);
        acc_fp8x4((int)d1.x, acc); acc_fp8x4((int)d1.y, acc + 4);
        acc_fp8x4((int)d2.x, acc); acc_fp8x4((int)d2.y, acc + 4);
        acc_fp8x4((int)d3.x, acc); acc_fp8x4((int)d3.y, acc + 4);
    }
    for (; k < k1; k += 2) {
        int s0 = sedge[k];
        uint2 d0 = *(const uint2*)&H[(size_t)s0 * HID_C + c0];
        acc_fp8x4((int)d0.x, acc);
        acc_fp8x4((int)d0.y, acc + 4);
    }

    // combine the 2 group partials
#pragma unroll
    for (int j = 0; j < 8; j++) acc[j] += __shfl_xor(acc[j], 32, 64);

    if (g == 0) {
        const float di = dinv[node];
        bf16x8 o;
#pragma unroll
        for (int j = 0; j < 8; j++)
            o[j] = (short)f2bf(fmaxf(di * acc[j] + bias[c0 + j], 0.0f));
        *(bf16x8*)&out[(size_t)node * HID_C + c0] = o;
    }
}

// Layer-2 gather: H rows bf16, prescaled by dinv[src]. 4 groups of 16 lanes;
// lane covers 8 channels (16B bf16 load). fp32 output.
__global__ __launch_bounds__(256) void gather2_bf16(const int* __restrict__ offsets,
                                                    const int* __restrict__ sedge,
                                                    const unsigned short* __restrict__ H,
                                                    const float* __restrict__ dinv,
                                                    const float* __restrict__ bias,
                                                    float* __restrict__ out) {
    const int node = blockIdx.x * 4 + (threadIdx.x >> 6);
    if (node >= N_NODES) return;
    const int ln = threadIdx.x & 63;
    const int g = ln >> 4;   // 4 groups
    const int l = ln & 15;
    const int c0 = l * 8;

    float acc[8] = {};
    if (g == 0) {
        bf16x8 h = *(const bf16x8*)&H[(size_t)node * OUT_C + c0];
#pragma unroll
        for (int j = 0; j < 8; j++) acc[j] = bf2f((unsigned short)h[j]);
    }

    int k = offsets[node] + g;
    const int k1 = offsets[node + 1];
    for (; k + 12 < k1; k += 16) {  // 4-deep unroll, group stride 4
        int s0 = sedge[k], s1 = sedge[k + 4], s2 = sedge[k + 8], s3 = sedge[k + 12];
        bf16x8 h0 = *(const bf16x8*)&H[(size_t)s0 * OUT_C + c0];
        bf16x8 h1 = *(const bf16x8*)&H[(size_t)s1 * OUT_C + c0];
        bf16x8 h2 = *(const bf16x8*)&H[(size_t)s2 * OUT_C + c0];
        bf16x8 h3 = *(const bf16x8*)&H[(size_t)s3 * OUT_C + c0];
#pragma unroll
        for (int j = 0; j < 8; j++) {
            acc[j] += bf2f((unsigned short)h0[j]);
            acc[j] += bf2f((unsigned short)h1[j]);
            acc[j] += bf2f((unsigned short)h2[j]);
            acc[j] += bf2f((unsigned short)h3[j]);
        }
    }
    for (; k < k1; k += 4) {
        int s0 = sedge[k];
        bf16x8 h0 = *(const bf16x8*)&H[(size_t)s0 * OUT_C + c0];
#pragma unroll
        for (int j = 0; j < 8; j++) acc[j] += bf2f((unsigned short)h0[j]);
    }

#pragma unroll
    for (int m = 16; m < 64; m <<= 1) {
#pragma unroll
        for (int j = 0; j < 8; j++) acc[j] += __shfl_xor(acc[j], m, 64);
    }

    if (g == 0) {
        const float di = dinv[node];
        float o[8];
#pragma unroll
        for (int j = 0; j < 8; j++) o[j] = di * acc[j] + bias[c0 + j];
        *(float4*)&out[(size_t)node * OUT_C + c0] = make_float4(o[0], o[1], o[2], o[3]);
        *(float4*)&out[(size_t)node * OUT_C + c0 + 4] = make_float4(o[4], o[5], o[6], o[7]);
    }
}

// ---------------------------------------------------------------- launcher
extern "C" void kernel_launch(void* const* d_in, const int* in_sizes, int n_in,
                              void* d_out, int out_size, void* d_ws, size_t ws_size,
                              hipStream_t stream) {
    const float* x  = (const float*)d_in[0];
    const int*   ei = (const int*)d_in[1];
    const float* W1 = (const float*)d_in[2];
    const float* b1 = (const float*)d_in[3];
    const float* W2 = (const float*)d_in[4];
    const float* b2 = (const float*)d_in[5];
    float* out = (float*)d_out;

    // workspace layout (4-byte words), same as known-good R2 (68.3 MiB).
    int*   counts     = (int*)d_ws;                          // 50048
    int*   offsets    = counts + 50048;                      // 50052 (+sentinel)
    int*   woff       = offsets + 50052;                     // 50048
    int*   bsums      = woff + 50048;                        // 64
    float* dinv       = (float*)(bsums + 64);                // 50048
    int*   sedge      = (int*)(dinv + 50048);                // 800000 (src only)
    unsigned short* W1T = (unsigned short*)(sedge + 800000);          // 131072 sh
    unsigned short* W2T = W1T + 131072;                               // 32768 sh
    unsigned short* xb  = W2T + 32768;                                // 25.6M sh region
    unsigned char*  H1  = (unsigned char*)(xb + (size_t)N_NODES * IN_C);  // 12.8MB fp8
    unsigned short* A1b = xb;                                         // overlay
    unsigned short* H2  = xb + (size_t)N_NODES * HID_C;               // overlay

    // CSR build + norm
    zero_counts_kernel<<<(N_NODES + 255) / 256, 256, 0, stream>>>(counts);
    count_kernel<<<(N_EDGES + 255) / 256, 256, 0, stream>>>(ei, counts);
    scan_part_kernel<<<SCAN_BLOCKS, 256, 0, stream>>>(counts, offsets, bsums);
    scan_sums_kernel<<<1, 64, 0, stream>>>(bsums);
    add_dinv_kernel<<<(N_NODES + 255) / 256, 256, 0, stream>>>(offsets, bsums, woff, counts, dinv);
    fill_kernel<<<(N_EDGES + 255) / 256, 256, 0, stream>>>(ei, woff, sedge);

    // weight casts (tiny)
    tcast_kernel<<<(IN_C * HID_C) / 256, 256, 0, stream>>>(W1, W1T, IN_C, HID_C);
    tcast_kernel<<<(HID_C * OUT_C) / 256, 256, 0, stream>>>(W2, W2T, HID_C, OUT_C);

    // layer 1: H1 = fp8( dinv[row] * (bf16(x) @ W1T^T) )  (cast fused, x read once)
    gemm1_fused<<<(N_NODES + 63) / 64, 256, 0, stream>>>(x, W1T, H1, dinv);
    gather1_fp8<<<(N_NODES + 3) / 4, 256, 0, stream>>>(offsets, sedge, H1, dinv, b1, A1b);

    // layer 2: H2 = bf16( dinv[row] * (A1b @ W2T^T) )
    gemm2_db<<<(N_NODES + 63) / 64, 256, 0, stream>>>(A1b, W2T, H2, dinv);
    gather2_bf16<<<(N_NODES + 3) / 4, 256, 0, stream>>>(offsets, sedge, H2, dinv, b2, out);
}